// Round 5
// baseline (1551.348 us; speedup 1.0000x reference)
//
#include <hip/hip_runtime.h>

#define T_STEPS 1000
#define DT 0.1f
#define HIDDEN 128
#define N_AGENTS 1024

// tanh(x) = 1 - 2/(exp(2x)+1); exact at +/-inf, ~1e-7 rel error.
__device__ __forceinline__ float tanh_fast(float x) {
    float e = __expf(2.0f * x);
    return 1.0f - 2.0f * __builtin_amdgcn_rcpf(e + 1.0f);
}

// One agent per block of 256 threads (4 waves). Lane tid owns ROW tid>>1 of
// W1 and K-HALF tid&1 (history entries 16*half .. 16*half+15): 64 weight
// floats per lane. 64 + ~45 working VGPRs fits the 128-VGPR budget of
// 4 waves/EU (pinned via amdgpu_waves_per_eu(4,4)), so the allocator keeps
// the weights register-resident instead of re-loading them every step
// (R2-R4 showed 128 floats/lane ALWAYS gets demoted to per-step reloads).
//
// Per step: 64 FMA -> pair-combine h via shfl_xor(1) -> parity-split
// layer-2 butterfly (even lanes sum W2[0]h, odd lanes W2[1]h, offsets
// 2..32) -> cross-wave combine of 8 floats through parity-double-buffered
// LDS with ONE barrier -> uniform dynamics -> push into per-wave-private
// history ring (no barrier: same-wave LDS RAW ordered by lgkmcnt).
__global__ __launch_bounds__(256)
__attribute__((amdgpu_waves_per_eu(4, 4)))
void sim_kernel(const float* __restrict__ target_pos,
                const float* __restrict__ logsigma,
                const float* __restrict__ x_inits,
                const float* __restrict__ W1,
                const float* __restrict__ b1,
                const float* __restrict__ W2,
                const float* __restrict__ b2,
                float2* __restrict__ ws) {
    const int agent = blockIdx.x;
    const int tid  = threadIdx.x;   // 0..255
    const int wave = tid >> 6;      // 0..3
    const int lane = tid & 63;
    const int row  = tid >> 1;      // 0..127 : W1/W2 column (hidden unit)
    const int half = tid & 1;       // k-half: history entries 16h..16h+15

    __shared__ float4 ring[4][64];  // per-wave private doubled ring
    __shared__ float  part[2][8];   // [parity][wave*2 + (0:p0 | 1:p1)]

    const float tx0 = target_pos[0], ty0 = target_pos[1];
    const float tx1 = target_pos[2], ty1 = target_pos[3];
    const float tx2 = target_pos[4], ty2 = target_pos[5];
    const float is0 = 1.0f / expf(logsigma[0]);
    const float is1 = 1.0f / expf(logsigma[1]);
    const float is2 = 1.0f / expf(logsigma[2]);

    // 48 position weights + 16 conc weights for (row, half).
    float wp[48], wc[16];
    {
        const float4* Wv = (const float4*)(W1 + row * 128 + 48 * half);
        #pragma unroll
        for (int i = 0; i < 12; ++i) {
            float4 v = Wv[i];
            wp[4*i] = v.x; wp[4*i+1] = v.y; wp[4*i+2] = v.z; wp[4*i+3] = v.w;
        }
        const float4* Wc = (const float4*)(W1 + row * 128 + 96 + 16 * half);
        #pragma unroll
        for (int i = 0; i < 4; ++i) {
            float4 v = Wc[i];
            wc[4*i] = v.x; wc[4*i+1] = v.y; wc[4*i+2] = v.z; wc[4*i+3] = v.w;
        }
    }
    const float b1r   = half ? 0.0f : b1[row];      // bias counted once/row
    const float w2sel = W2[half * HIDDEN + row];    // even:W2 row0, odd:row1
    const float b2x = b2[0], b2y = b2[1];

    float x  = x_inits[3 * agent];
    float y  = x_inits[3 * agent + 1];
    float th = x_inits[3 * agent + 2];

    auto conc = [&](float px, float py) {
        float dx0 = px - tx0, dy0 = py - ty0;
        float dx1 = px - tx1, dy1 = py - ty1;
        float dx2 = px - tx2, dy2 = py - ty2;
        float c  = is0 * __expf(-(dx0*dx0 + dy0*dy0) * is0);
        c       += is1 * __expf(-(dx1*dx1 + dy1*dy1) * is1);
        c       += is2 * __expf(-(dx2*dx2 + dy2*dy2) * is2);
        return c;
    };

    // Initial history: every slot = initial state (each wave fills its ring).
    float c0 = conc(x, y);
    ring[wave][lane] = make_float4(x, y, th, c0);
    __syncthreads();

    int base = 32;                 // window [base, base+31], newest first
    const int hoff = half << 4;    // 0 or 16
    float S_c = 0.f, S_u = 0.f;

    for (int t = 0; t < T_STEPS; ++t) {
        // ---- layer 1 (half-row dot): 64 FMAs ----
        float ax = 0.f, ay = 0.f, az = 0.f, aw = b1r;
        #pragma unroll
        for (int m = 0; m < 16; ++m) {
            // 2 distinct addrs per wave (even/odd) -> 2-way, free (m136)
            float4 e = ring[wave][base + hoff + m];
            ax = fmaf(wp[3*m],     e.x, ax);
            ay = fmaf(wp[3*m + 1], e.y, ay);
            az = fmaf(wp[3*m + 2], e.z, az);
            aw = fmaf(wc[m],       e.w, aw);
        }
        float partial = (ax + ay) + (az + aw);
        partial += __shfl_xor(partial, 1);          // combine k-halves
        float h = fmaxf(partial, 0.f);

        // ---- layer 2: parity butterfly (offsets 2..32) ----
        float q = w2sel * h;
        #pragma unroll
        for (int off = 2; off <= 32; off <<= 1) q += __shfl_xor(q, off);
        // even lanes: wave-sum of W2[0]*h ; odd lanes: W2[1]*h
        if (lane < 2) part[t & 1][wave * 2 + lane] = q;
        __syncthreads();
        const float* pp = part[t & 1];
        float P0 = (pp[0] + pp[2]) + (pp[4] + pp[6]);
        float P1 = (pp[1] + pp[3]) + (pp[5] + pp[7]);

        // ---- controls + dynamics (uniform on all lanes) ----
        float v = tanh_fast(P0 + b2x);
        float w = tanh_fast(P1 + b2y);
        S_u += v * v + w * w;

        float sn = __sinf(th), cs = __cosf(th);
        x  = fmaf(DT * v, cs, x);
        y  = fmaf(DT * v, sn, y);
        th = fmaf(DT, w, th);

        float cn = conc(x, y);
        S_c += cn;

        // ---- push into own ring (dual write keeps window unwrapped) ----
        int qi = (base - 1) & 31;
        if (lane == 0) {
            float4 e = make_float4(x, y, th, cn);
            ring[wave][qi]      = e;
            ring[wave][qi + 32] = e;
        }
        base = qi;
        // no second barrier: ring is wave-private; part[] is parity-
        // double-buffered and each wave passes the next barrier before
        // its parity slot is rewritten.
    }

    if (tid == 0) ws[agent] = make_float2(S_c, S_u);
}

__global__ void reduce_kernel(const float2* __restrict__ ws,
                              float* __restrict__ out) {
    const int tid = threadIdx.x;  // 256 threads
    float sc = 0.f, su = 0.f;
    for (int i = tid; i < N_AGENTS; i += 256) {
        float2 v = ws[i];
        sc += v.x;
        su += v.y;
    }
    #pragma unroll
    for (int off = 32; off > 0; off >>= 1) {
        sc += __shfl_xor(sc, off);
        su += __shfl_xor(su, off);
    }
    __shared__ float2 partw[4];
    int wave = tid >> 6;
    if ((tid & 63) == 0) partw[wave] = make_float2(sc, su);
    __syncthreads();
    if (tid == 0) {
        float SC = partw[0].x + partw[1].x + partw[2].x + partw[3].x;
        float SU = partw[0].y + partw[1].y + partw[2].y + partw[3].y;
        const float invNT  = 1.0f / (float)(N_AGENTS * T_STEPS);
        const float invNT2 = 1.0f / (float)(N_AGENTS * T_STEPS * 2);
        out[0] = -SC * invNT + SU * invNT2;
    }
}

extern "C" void kernel_launch(void* const* d_in, const int* in_sizes, int n_in,
                              void* d_out, int out_size, void* d_ws, size_t ws_size,
                              hipStream_t stream) {
    const float* target_pos = (const float*)d_in[0];
    const float* logsigma   = (const float*)d_in[1];
    const float* x_inits    = (const float*)d_in[2];
    const float* W1         = (const float*)d_in[3];
    const float* b1         = (const float*)d_in[4];
    const float* W2         = (const float*)d_in[5];
    const float* b2         = (const float*)d_in[6];
    float2* ws = (float2*)d_ws;

    sim_kernel<<<N_AGENTS, 256, 0, stream>>>(target_pos, logsigma, x_inits,
                                             W1, b1, W2, b2, ws);
    reduce_kernel<<<1, 256, 0, stream>>>(ws, (float*)d_out);
}

// Round 6
// 1249.874 us; speedup vs baseline: 1.2412x; 1.2412x over previous
//
#include <hip/hip_runtime.h>

#define T_STEPS 1000
#define DT 0.1f
#define HIDDEN 128
#define N_AGENTS 1024

// tanh(x) = 1 - 2/(exp(2x)+1); exact at +/-inf, ~1e-7 rel error.
__device__ __forceinline__ float tanh_fast(float x) {
    float e = __expf(2.0f * x);
    return 1.0f - 2.0f * __builtin_amdgcn_rcpf(e + 1.0f);
}

// Opaque 16B load: the compiler cannot remat/sink an asm result, so values
// loaded this way MUST stay register-resident (or be spilled to scratch,
// which the RA won't do while pressure <= the waves_per_eu(4,4) budget).
// R2-R5 proved plain loads of loop-invariant weights always get sunk back
// into the t-loop (VGPR_Count 56..116 with 64-128 weight floats/lane).
__device__ __forceinline__ float4 opaque_load16(const float* p) {
    float4 v;
    asm volatile("global_load_dwordx4 %0, %1, off\n\ts_waitcnt vmcnt(0)"
                 : "=v"(v)
                 : "v"((unsigned long long)(uintptr_t)p)
                 : "memory");
    return v;
}

// One agent per block of 256 threads (4 waves). Thread tid owns W1 row
// tid>>1 and K-half tid&1 (history ages 16h..16h+15): 64 weight floats in
// VGPRs via opaque asm loads. Budget: 64 + ~45 working < 128 VGPRs
// (4 waves/EU, pinned).
//
// History ring: per-wave-private DOUBLED ring (64 slots), duplicated into
// an odd-lane copy offset by 64B mod 128B so the wave's two distinct b128
// addresses hit DISJOINT bank quads (R5's single copy put them 256B apart
// = same quad -> 2.6e8 conflict cycles).
//   per-wave slab: [0..63] even copy | 64..67 pad (64B) | [68..131] odd copy
//   even lane reads slab[base+m], odd lane reads slab[68+16 + base+m].
__global__ __launch_bounds__(256)
__attribute__((amdgpu_waves_per_eu(4, 4)))
void sim_kernel(const float* __restrict__ target_pos,
                const float* __restrict__ logsigma,
                const float* __restrict__ x_inits,
                const float* W1,
                const float* __restrict__ b1,
                const float* __restrict__ W2,
                const float* __restrict__ b2,
                float2* __restrict__ ws) {
    const int agent = blockIdx.x;
    const int tid  = threadIdx.x;   // 0..255
    const int wave = tid >> 6;      // 0..3
    const int lane = tid & 63;
    const int row  = tid >> 1;      // 0..127 : hidden unit
    const int half = tid & 1;       // k-half: ages 16h..16h+15

    // 136 float4 per wave: stride 2176B = 544 dwords = 0 mod 32 banks,
    // so every wave's slab has identical bank alignment.
    __shared__ float4 slab[4][136];
    __shared__ float  part[2][8];   // [parity][wave*2 + (0:p0 | 1:p1)]

    const float tx0 = target_pos[0], ty0 = target_pos[1];
    const float tx1 = target_pos[2], ty1 = target_pos[3];
    const float tx2 = target_pos[4], ty2 = target_pos[5];
    const float is0 = 1.0f / expf(logsigma[0]);
    const float is1 = 1.0f / expf(logsigma[1]);
    const float is2 = 1.0f / expf(logsigma[2]);

    // --- 64 weights/lane via opaque loads (cannot be sunk into the loop) ---
    // w[0..47]  = W1[row, 48*half .. 48*half+47]   (position weights)
    // w[48..63] = W1[row, 96+16*half .. +15]       (concentration weights)
    const float* rowp = W1 + row * 128;
    float4 WV[16];
    #pragma unroll
    for (int i = 0; i < 12; ++i) WV[i] = opaque_load16(rowp + 48 * half + 4 * i);
    #pragma unroll
    for (int i = 0; i < 4; ++i)  WV[12 + i] = opaque_load16(rowp + 96 + 16 * half + 4 * i);
    float w[64];
    #pragma unroll
    for (int i = 0; i < 16; ++i) {
        w[4*i] = WV[i].x; w[4*i+1] = WV[i].y; w[4*i+2] = WV[i].z; w[4*i+3] = WV[i].w;
    }

    const float b1r   = half ? 0.0f : b1[row];      // bias counted once/row
    const float w2sel = W2[half * HIDDEN + row];    // even: W2 row0, odd: row1
    const float b2x = b2[0], b2y = b2[1];

    float x  = x_inits[3 * agent];
    float y  = x_inits[3 * agent + 1];
    float th = x_inits[3 * agent + 2];

    auto conc = [&](float px, float py) {
        float dx0 = px - tx0, dy0 = py - ty0;
        float dx1 = px - tx1, dy1 = py - ty1;
        float dx2 = px - tx2, dy2 = py - ty2;
        float c  = is0 * __expf(-(dx0*dx0 + dy0*dy0) * is0);
        c       += is1 * __expf(-(dx1*dx1 + dy1*dy1) * is1);
        c       += is2 * __expf(-(dx2*dx2 + dy2*dy2) * is2);
        return c;
    };

    // Initial history: every slot of both copies = initial state.
    float c0 = conc(x, y);
    {
        float4 e0 = make_float4(x, y, th, c0);
        slab[wave][lane]      = e0;   // even copy
        slab[wave][68 + lane] = e0;   // odd copy (64B-shifted bank phase)
    }
    __syncthreads();

    // Odd lanes read ages base+16+m from their own copy.
    const float4* myring = half ? &slab[wave][68 + 16] : &slab[wave][0];

    int base = 32;                 // window [base, base+31], newest first
    float S_c = 0.f, S_u = 0.f;

    for (int t = 0; t < T_STEPS; ++t) {
        // ---- layer 1 (half-row dot): 64 FMAs, conflict-free b128 reads ----
        float ax = 0.f, ay = 0.f, az = 0.f, aw = b1r;
        #pragma unroll
        for (int m = 0; m < 16; ++m) {
            float4 e = myring[base + m];
            ax = fmaf(w[3*m],     e.x, ax);
            ay = fmaf(w[3*m + 1], e.y, ay);
            az = fmaf(w[3*m + 2], e.z, az);
            aw = fmaf(w[48 + m],  e.w, aw);
        }
        float partial = (ax + ay) + (az + aw);
        partial += __shfl_xor(partial, 1);          // combine k-halves
        float h = fmaxf(partial, 0.f);

        // ---- layer 2: parity butterfly (offsets 2..32) ----
        float q = w2sel * h;
        #pragma unroll
        for (int off = 2; off <= 32; off <<= 1) q += __shfl_xor(q, off);
        // even lanes: wave-sum of W2[0]*h ; odd lanes: W2[1]*h
        if (lane < 2) part[t & 1][wave * 2 + lane] = q;
        __syncthreads();
        const float* pp = part[t & 1];
        float P0 = (pp[0] + pp[2]) + (pp[4] + pp[6]);
        float P1 = (pp[1] + pp[3]) + (pp[5] + pp[7]);

        // ---- controls + dynamics (uniform on all lanes) ----
        float v = tanh_fast(P0 + b2x);
        float wv = tanh_fast(P1 + b2y);
        S_u += v * v + wv * wv;

        float sn = __sinf(th), cs = __cosf(th);
        x  = fmaf(DT * v, cs, x);
        y  = fmaf(DT * v, sn, y);
        th = fmaf(DT, wv, th);

        float cn = conc(x, y);
        S_c += cn;

        // ---- push into both copies of own ring (dual write keeps the
        //      doubled window unwrapped). lane0 -> even copy, lane1 -> odd.
        int qi = (base - 1) & 31;
        if (lane < 2) {
            float4 e = make_float4(x, y, th, cn);
            int o = (lane == 0) ? 0 : 68;
            slab[wave][o + qi]      = e;
            slab[wave][o + qi + 32] = e;
        }
        base = qi;
        // no second barrier: slab is wave-private; part[] is parity-
        // double-buffered.
    }

    if (tid == 0) ws[agent] = make_float2(S_c, S_u);
}

__global__ void reduce_kernel(const float2* __restrict__ ws,
                              float* __restrict__ out) {
    const int tid = threadIdx.x;  // 256 threads
    float sc = 0.f, su = 0.f;
    for (int i = tid; i < N_AGENTS; i += 256) {
        float2 v = ws[i];
        sc += v.x;
        su += v.y;
    }
    #pragma unroll
    for (int off = 32; off > 0; off >>= 1) {
        sc += __shfl_xor(sc, off);
        su += __shfl_xor(su, off);
    }
    __shared__ float2 partw[4];
    int wave = tid >> 6;
    if ((tid & 63) == 0) partw[wave] = make_float2(sc, su);
    __syncthreads();
    if (tid == 0) {
        float SC = partw[0].x + partw[1].x + partw[2].x + partw[3].x;
        float SU = partw[0].y + partw[1].y + partw[2].y + partw[3].y;
        const float invNT  = 1.0f / (float)(N_AGENTS * T_STEPS);
        const float invNT2 = 1.0f / (float)(N_AGENTS * T_STEPS * 2);
        out[0] = -SC * invNT + SU * invNT2;
    }
}

extern "C" void kernel_launch(void* const* d_in, const int* in_sizes, int n_in,
                              void* d_out, int out_size, void* d_ws, size_t ws_size,
                              hipStream_t stream) {
    const float* target_pos = (const float*)d_in[0];
    const float* logsigma   = (const float*)d_in[1];
    const float* x_inits    = (const float*)d_in[2];
    const float* W1         = (const float*)d_in[3];
    const float* b1         = (const float*)d_in[4];
    const float* W2         = (const float*)d_in[5];
    const float* b2         = (const float*)d_in[6];
    float2* ws = (float2*)d_ws;

    sim_kernel<<<N_AGENTS, 256, 0, stream>>>(target_pos, logsigma, x_inits,
                                             W1, b1, W2, b2, ws);
    reduce_kernel<<<1, 256, 0, stream>>>(ws, (float*)d_out);
}